// Round 1
// baseline (377.582 us; speedup 1.0000x reference)
//
#include <hip/hip_runtime.h>

typedef unsigned short u16;
typedef unsigned int   u32;

#define BATCH  8192
#define DIM    100      // D
#define HID    110      // H
#define TSUB   19       // T = N-1 subnets
#define NSTEP  20       // N scan steps
#define KP     128      // padded K for MFMA
#define NPAD   112      // padded N (output cols) for tiles/storage
#define BN_EPS 1e-6f
#define DT_C   0.05f

typedef __bf16 v8bf __attribute__((ext_vector_type(8)));
typedef float  v4f  __attribute__((ext_vector_type(4)));

__device__ __forceinline__ u16 f2bf(float f) {
    u32 u = __float_as_uint(f);
    return (u16)((u + 0x7fffu + ((u >> 16) & 1u)) >> 16);   // RNE
}
__device__ __forceinline__ float bf2f(u16 h) {
    return __uint_as_float(((u32)h) << 16);
}

// ---------------------------------------------------------------------------
// Pass 1: batch stats of x[:, d, n] over b, for all 2100 (d,n) pairs.
// x rows are contiguous (2100 floats) -> fully coalesced streaming read.
// ---------------------------------------------------------------------------
__global__ void stats0_kernel(const float* __restrict__ x,
                              float* __restrict__ sum0, float* __restrict__ sq0) {
    const int tid = threadIdx.x;
    const int b0 = blockIdx.x * 64;
    float s[9], q[9];
#pragma unroll
    for (int j = 0; j < 9; j++) { s[j] = 0.f; q[j] = 0.f; }
    for (int b = b0; b < b0 + 64; b++) {
        const float* row = x + (size_t)b * 2100;
#pragma unroll
        for (int j = 0; j < 9; j++) {
            int idx = tid + j * 256;
            if (idx < 2100) { float v = row[idx]; s[j] += v; q[j] += v * v; }
        }
    }
#pragma unroll
    for (int j = 0; j < 9; j++) {
        int idx = tid + j * 256;
        if (idx < 2100) { atomicAdd(&sum0[idx], s[j]); atomicAdd(&sq0[idx], q[j]); }
    }
}

__global__ void finalize0_kernel(const float* __restrict__ sum0, const float* __restrict__ sq0,
                                 const float* __restrict__ g, const float* __restrict__ be,
                                 float* __restrict__ a, float* __restrict__ c) {
    int i = blockIdx.x * blockDim.x + threadIdx.x;   // over T*D
    if (i >= TSUB * DIM) return;
    int t = i / DIM, d = i % DIM;
    int idx = d * 21 + (t + 1);                      // x[:, d, t+1]
    float m = sum0[idx] * (1.f / BATCH);
    float v = sq0[idx] * (1.f / BATCH) - m * m;
    float rstd = rsqrtf(v + BN_EPS);
    float ga = g[i] * rstd;
    a[i] = ga;
    c[i] = be[i] - m * ga;
}

__global__ void finalize_kernel(const float* __restrict__ sum, const float* __restrict__ sq,
                                const float* __restrict__ g, const float* __restrict__ be,
                                float* __restrict__ a, float* __restrict__ c,
                                int nout, float scale) {
    int i = blockIdx.x * blockDim.x + threadIdx.x;   // over T*nout
    if (i >= TSUB * nout) return;
    float m = sum[i] * (1.f / BATCH);
    float v = sq[i] * (1.f / BATCH) - m * m;
    float rstd = rsqrtf(v + BN_EPS);
    float ga = g[i] * rstd;
    a[i] = ga * scale;
    c[i] = (be[i] - m * ga) * scale;
}

// ---------------------------------------------------------------------------
// GEMM: per (t, m-tile) block. C[128 x NPAD] = affine(A)[128 x KREAL] @ W[KREAL x NOUT]
// MODE 0: A = x slice (f32, strided, affine only)
// MODE 1: A = bf16 buffer [T][B][NPAD], affine + relu
// Epilogue: stores pre-BN result (bf16) and accumulates column sums / sumsq.
// ---------------------------------------------------------------------------
template <int KREAL, int NOUT, int MODE>
__global__ void gemm_kernel(const void* __restrict__ Asrc,
                            const float* __restrict__ W,          // [T][KREAL][NOUT]
                            const float* __restrict__ aArr,       // [T][KREAL]
                            const float* __restrict__ cArr,       // [T][KREAL]
                            u16* __restrict__ Hout,               // [T][B][NPAD]
                            float* __restrict__ sumArr,           // [T][NOUT]
                            float* __restrict__ sqArr) {          // [T][NOUT]
    __shared__ __align__(16) u16 Alds[128 * KP];   // 32 KB, 16B-chunk XOR swizzle
    __shared__ __align__(16) u16 Blds[NPAD * KP];  // 28 KB, B stored transposed [n][k]
    __shared__ float s_sum[NPAD], s_sq[NPAD];

    const int tid = threadIdx.x;
    const int mt = blockIdx.x;
    const int t  = blockIdx.y;
    const int brow0 = mt * 128;

    // zero LDS (padding must be 0 on the B side; A side zeroed for cleanliness)
    {
        uint4 z = {0, 0, 0, 0};
        uint4* a4 = (uint4*)Alds;
        uint4* b4 = (uint4*)Blds;
        for (int i = tid; i < 128 * KP / 8; i += 256) a4[i] = z;
        for (int i = tid; i < NPAD * KP / 8; i += 256) b4[i] = z;
        if (tid < NPAD) { s_sum[tid] = 0.f; s_sq[tid] = 0.f; }
    }
    __syncthreads();

    // ---- stage A (affine [+relu]) as bf16, swizzled 16B chunks ----
    const float* aAff = aArr + t * KREAL;
    const float* cAff = cArr + t * KREAL;
    const int NCH = (KREAL + 7) / 8;   // chunks containing real data
    for (int cidx = tid; cidx < 128 * NCH; cidx += 256) {
        int row = cidx / NCH;
        int kc  = cidx % NCH;
        int k0  = kc * 8;
        float v[8];
        if (MODE == 0) {
            const float* xrow = (const float*)Asrc + (size_t)(brow0 + row) * 2100 + (t + 1);
#pragma unroll
            for (int j = 0; j < 8; j++) {
                int k = k0 + j;
                v[j] = (k < KREAL) ? (xrow[k * 21] * aAff[k] + cAff[k]) : 0.f;
            }
        } else {
            const u16* hrow = (const u16*)Asrc + ((size_t)t * BATCH + brow0 + row) * NPAD + k0;
            u16 hv[8];
            *(uint4*)hv = *(const uint4*)hrow;       // 16B aligned (NPAD*2 and k0*2 are 16B multiples)
#pragma unroll
            for (int j = 0; j < 8; j++) {
                int k = k0 + j;
                float hf = bf2f(hv[j]);
                float av = (k < KREAL) ? fmaf(hf, aAff[k], cAff[k]) : 0.f;
                v[j] = fmaxf(av, 0.f);
            }
        }
        u16 pk[8];
#pragma unroll
        for (int j = 0; j < 8; j++) pk[j] = f2bf(v[j]);
        int swc = kc ^ (row & 7);
        *(uint4*)&Alds[row * KP + swc * 8] = *(uint4*)pk;
    }

    // ---- stage B transposed: Blds[n][k] = W[t][k][n] (coalesced global reads) ----
    const float* Wt = W + (size_t)t * KREAL * NOUT;
    for (int i = tid; i < KREAL * NOUT; i += 256) {
        int k = i / NOUT, n = i % NOUT;
        int swc = (k >> 3) ^ (n & 7);
        Blds[n * KP + swc * 8 + (k & 7)] = f2bf(Wt[i]);
    }
    __syncthreads();

    // ---- MFMA: wave owns 32 rows x 112 cols = 2 m-frags x 7 n-frags ----
    const int lane = tid & 63;
    const int wv   = tid >> 6;
    const int r0   = lane & 15;
    const int q    = lane >> 4;
    const int moff = wv * 32;

    v4f acc[2][7];
#pragma unroll
    for (int i = 0; i < 2; i++)
#pragma unroll
        for (int j = 0; j < 7; j++) { v4f z = {0.f, 0.f, 0.f, 0.f}; acc[i][j] = z; }

#pragma unroll
    for (int ks = 0; ks < 4; ks++) {
        int cbase = ks * 4 + q;   // 16B chunk index along K for this lane quarter
        v8bf afr[2];
#pragma unroll
        for (int mf = 0; mf < 2; mf++) {
            int row = moff + mf * 16 + r0;
            afr[mf] = *(const v8bf*)&Alds[row * KP + ((cbase ^ (row & 7)) * 8)];
        }
#pragma unroll
        for (int nf = 0; nf < 7; nf++) {
            int nr = nf * 16 + r0;
            v8bf bfr = *(const v8bf*)&Blds[nr * KP + ((cbase ^ (nr & 7)) * 8)];
            acc[0][nf] = __builtin_amdgcn_mfma_f32_16x16x32_bf16(afr[0], bfr, acc[0][nf], 0, 0, 0);
            acc[1][nf] = __builtin_amdgcn_mfma_f32_16x16x32_bf16(afr[1], bfr, acc[1][nf], 0, 0, 0);
        }
    }

    // ---- epilogue: store bf16 pre-BN values + column stats ----
#pragma unroll
    for (int mf = 0; mf < 2; mf++) {
#pragma unroll
        for (int nf = 0; nf < 7; nf++) {
            int n = nf * 16 + r0;
#pragma unroll
            for (int rg = 0; rg < 4; rg++) {
                int grow = brow0 + moff + mf * 16 + q * 4 + rg;
                Hout[((size_t)t * BATCH + grow) * NPAD + n] = f2bf(acc[mf][nf][rg]);
            }
        }
    }
#pragma unroll
    for (int nf = 0; nf < 7; nf++) {
        float cs = 0.f, cq = 0.f;
#pragma unroll
        for (int mf = 0; mf < 2; mf++)
#pragma unroll
            for (int rg = 0; rg < 4; rg++) {
                float vv = acc[mf][nf][rg];
                cs += vv; cq += vv * vv;
            }
        cs += __shfl_xor(cs, 16); cs += __shfl_xor(cs, 32);
        cq += __shfl_xor(cq, 16); cq += __shfl_xor(cq, 32);
        if (q == 0) {
            atomicAdd(&s_sum[nf * 16 + r0], cs);
            atomicAdd(&s_sq[nf * 16 + r0], cq);
        }
    }
    __syncthreads();
    if (tid < NOUT) {
        atomicAdd(&sumArr[t * NOUT + tid], s_sum[tid]);
        atomicAdd(&sqArr[t * NOUT + tid], s_sq[tid]);
    }
}

// ---------------------------------------------------------------------------
// Scan: lane-per-timestep (20 lanes per batch row, 3 rows per wave).
// dot[b,n] = sum_d z[n,b,d] * dw[b,d,n];  z[0] = z_init, z[n>=1] = affine3(out_pre).
// Then 20-step serial recursion via shuffles; mean_y via block-reduced atomics.
// ---------------------------------------------------------------------------
__global__ void scan_kernel(const float* __restrict__ dw,
                            const u16* __restrict__ zbuf,         // [T][B][NPAD]
                            const float* __restrict__ a3, const float* __restrict__ c3,
                            const float* __restrict__ z_init, const float* __restrict__ y_init,
                            float* __restrict__ yout, float* __restrict__ meanout) {
    __shared__ float a3l[TSUB * DIM], c3l[TSUB * DIM], zil[DIM];
    __shared__ float bsum[NSTEP];
    const int tid = threadIdx.x;
    for (int i = tid; i < TSUB * DIM; i += 256) { a3l[i] = a3[i]; c3l[i] = c3[i]; }
    if (tid < DIM) zil[tid] = z_init[tid];
    if (tid < NSTEP) bsum[tid] = 0.f;
    __syncthreads();

    const int wv = tid >> 6, lane = tid & 63;
    const int g = lane / 20, n = lane - g * 20;       // g==3 -> idle lanes 60..63
    const int b = (blockIdx.x * 4 + wv) * 3 + g;
    const bool active = (g < 3) && (b < BATCH);

    float dot = 0.f;
    if (active) {
        const float* dwb = dw + (size_t)b * (DIM * NSTEP) + n;
        if (n == 0) {
            for (int d = 0; d < DIM; d++) dot += zil[d] * dwb[d * NSTEP];
        } else {
            const int t = n - 1;
            const u16* zr = zbuf + ((size_t)t * BATCH + b) * NPAD;
            const float* al = a3l + t * DIM;
            const float* cl = c3l + t * DIM;
            for (int d = 0; d < DIM; d++) {
                float zv = fmaf(bf2f(zr[d]), al[d], cl[d]);
                dot += zv * dwb[d * NSTEP];
            }
        }
    }

    const float yi = y_init[0];
    float y = yi, ysave = 0.f;
#pragma unroll
    for (int i = 0; i < NSTEP; i++) {
        float dv = __shfl(dot, g * 20 + i, 64);
        y = y - DT_C * __sinf(y) + dv;
        if (i == n - 1) ysave = y;                    // lane n holds y_n (n>=1)
    }
    if (active && n == 0) yout[b] = y;                // y_final = y_20
    if (active && n >= 1) atomicAdd(&bsum[n], ysave);
    __syncthreads();
    if (tid >= 1 && tid < NSTEP) atomicAdd(&meanout[tid], bsum[tid] * (1.f / BATCH));
    if (blockIdx.x == 0 && tid == 0) meanout[0] = yi; // mean of constant y0
}

// ---------------------------------------------------------------------------
extern "C" void kernel_launch(void* const* d_in, const int* in_sizes, int n_in,
                              void* d_out, int out_size, void* d_ws, size_t ws_size,
                              hipStream_t stream) {
    const float* dw     = (const float*)d_in[0];
    const float* x      = (const float*)d_in[1];
    const float* y_init = (const float*)d_in[3];
    const float* z_init = (const float*)d_in[4];
    const float* g0 = (const float*)d_in[5];
    const float* b0 = (const float*)d_in[6];
    const float* W0 = (const float*)d_in[7];
    const float* g1 = (const float*)d_in[8];
    const float* b1 = (const float*)d_in[9];
    const float* W1 = (const float*)d_in[10];
    const float* g2 = (const float*)d_in[11];
    const float* b2 = (const float*)d_in[12];
    const float* W2 = (const float*)d_in[13];
    // d_in[14] = bias2: provably cancelled by the following BatchNorm -> unused
    const float* g3 = (const float*)d_in[15];
    const float* b3 = (const float*)d_in[16];

    char* ws = (char*)d_ws;
    size_t off = 0;
    auto alloc = [&](size_t bytes) -> void* {
        off = (off + 255) & ~(size_t)255;
        void* p = ws + off;
        off += bytes;
        return p;
    };

    // stats block (memset to 0 each launch), then affine params, then bf16 buffers
    const int nStats = 2100 * 2 + TSUB * HID * 2 * 2 + TSUB * DIM * 2;  // 16360 floats
    float* statsBlk = (float*)alloc((size_t)nStats * 4);
    float* sum0 = statsBlk;            float* sq0  = sum0 + 2100;
    float* sum1 = sq0 + 2100;          float* sq1  = sum1 + TSUB * HID;
    float* sum2 = sq1 + TSUB * HID;    float* sq2  = sum2 + TSUB * HID;
    float* sum3 = sq2 + TSUB * HID;    float* sq3  = sum3 + TSUB * DIM;

    float* a0 = (float*)alloc(TSUB * DIM * 4);  float* c0 = (float*)alloc(TSUB * DIM * 4);
    float* a1 = (float*)alloc(TSUB * HID * 4);  float* c1 = (float*)alloc(TSUB * HID * 4);
    float* a2 = (float*)alloc(TSUB * HID * 4);  float* c2 = (float*)alloc(TSUB * HID * 4);
    float* a3 = (float*)alloc(TSUB * DIM * 4);  float* c3 = (float*)alloc(TSUB * DIM * 4);

    const size_t hBytes = (size_t)TSUB * BATCH * NPAD * 2;   // ~34.9 MB
    u16* h0 = (u16*)alloc(hBytes);
    u16* h1 = (u16*)alloc(hBytes);
    u16* outbuf = h0;   // h0 is dead once gemm1 has consumed it

    float* yout = (float*)d_out;
    float* meanout = yout + BATCH;

    hipMemsetAsync(statsBlk, 0, (size_t)nStats * 4, stream);
    hipMemsetAsync(meanout, 0, NSTEP * 4, stream);

    stats0_kernel<<<128, 256, 0, stream>>>(x, sum0, sq0);
    finalize0_kernel<<<8, 256, 0, stream>>>(sum0, sq0, g0, b0, a0, c0);

    gemm_kernel<DIM, HID, 0><<<dim3(64, TSUB), 256, 0, stream>>>(x, W0, a0, c0, h0, sum1, sq1);
    finalize_kernel<<<9, 256, 0, stream>>>(sum1, sq1, g1, b1, a1, c1, HID, 1.f);

    gemm_kernel<HID, HID, 1><<<dim3(64, TSUB), 256, 0, stream>>>(h0, W1, a1, c1, h1, sum2, sq2);
    finalize_kernel<<<9, 256, 0, stream>>>(sum2, sq2, g2, b2, a2, c2, HID, 1.f);

    gemm_kernel<HID, DIM, 1><<<dim3(64, TSUB), 256, 0, stream>>>(h1, W2, a2, c2, outbuf, sum3, sq3);
    finalize_kernel<<<8, 256, 0, stream>>>(sum3, sq3, g3, b3, a3, c3, DIM, 1.f / DIM);

    scan_kernel<<<683, 256, 0, stream>>>(dw, outbuf, a3, c3, z_init, y_init, yout, meanout);
}

// Round 2
// 244.168 us; speedup vs baseline: 1.5464x; 1.5464x over previous
//
#include <hip/hip_runtime.h>

typedef unsigned short u16;
typedef unsigned int   u32;

#define BATCH  8192
#define DIM    100      // D
#define HID    110      // H
#define TSUB   19       // T = N-1 subnets
#define NSTEP  20       // N scan steps
#define KP     128      // padded K for MFMA
#define NPAD   112      // padded N (output cols) for tiles/storage
#define BN_EPS 1e-6f
#define DT_C   0.05f

#define SB       512                 // stats partial blocks
#define ROWS_PER (BATCH / SB)        // 16
#define SLICES   16                  // reduce slices (512/16 = 32 rows per slice)

typedef __bf16 v8bf __attribute__((ext_vector_type(8)));
typedef float  v4f  __attribute__((ext_vector_type(4)));

__device__ __forceinline__ u16 f2bf(float f) {
    u32 u = __float_as_uint(f);
    return (u16)((u + 0x7fffu + ((u >> 16) & 1u)) >> 16);   // RNE
}
__device__ __forceinline__ float bf2f(u16 h) {
    return __uint_as_float(((u32)h) << 16);
}
__device__ __forceinline__ void acc4(float4& s, float4& q, float4 v) {
    s.x += v.x; s.y += v.y; s.z += v.z; s.w += v.w;
    q.x += v.x * v.x; q.y += v.y * v.y; q.z += v.z * v.z; q.w += v.w * v.w;
}

// ---------------------------------------------------------------------------
// stats0 phase A: per-block partial sums over 16 batch rows, float4 loads.
// part layout: [SB][4200]: [0..2099] = col sums, [2100..4199] = col sumsq.
// ---------------------------------------------------------------------------
__global__ void stats0A(const float* __restrict__ x, float* __restrict__ part) {
    const int tid = threadIdx.x;
    const int b0 = blockIdx.x * ROWS_PER;
    float4 s0 = {0,0,0,0}, q0 = {0,0,0,0};
    float4 s1 = {0,0,0,0}, q1 = {0,0,0,0};
    float4 s2 = {0,0,0,0}, q2 = {0,0,0,0};
#pragma unroll 4
    for (int r = 0; r < ROWS_PER; r++) {
        const float4* row = (const float4*)(x + (size_t)(b0 + r) * 2100);
        float4 v0 = row[tid];
        float4 v1 = row[tid + 256];
        acc4(s0, q0, v0);
        acc4(s1, q1, v1);
        if (tid < 13) { float4 v2 = row[tid + 512]; acc4(s2, q2, v2); }
    }
    float* ps = part + (size_t)blockIdx.x * 4200;
    *(float4*)&ps[tid * 4]               = s0;
    *(float4*)&ps[1024 + tid * 4]        = s1;
    *(float4*)&ps[2100 + tid * 4]        = q0;
    *(float4*)&ps[2100 + 1024 + tid * 4] = q1;
    if (tid < 13) {
        *(float4*)&ps[2048 + tid * 4]        = s2;
        *(float4*)&ps[2100 + 2048 + tid * 4] = q2;
    }
}

// phase B: out[o] = sum over SB partial rows (16 slices of 32, atomic combine)
__global__ void stats0B(const float* __restrict__ part, float* __restrict__ out) {
    int gid = blockIdx.x * 256 + threadIdx.x;
    if (gid >= 4200 * SLICES) return;
    int slice = gid / 4200;
    int o = gid - slice * 4200;
    const float* p = part + (size_t)slice * (SB / SLICES) * 4200 + o;
    float acc = 0.f;
#pragma unroll 4
    for (int i = 0; i < SB / SLICES; i++) acc += p[(size_t)i * 4200];
    atomicAdd(&out[o], acc);
}

// ---------------------------------------------------------------------------
// GEMM: per (t, m-tile) block. C[128 x NPAD] = affine(A)[128 x KREAL] @ W[KREAL x NOUT]
// BN-affine params computed in-kernel from sumIn/sqIn (folds finalize kernel).
// MODE 0: A = x slice (f32, strided, affine only); stats idx = k*21 + (t+1)
// MODE 1: A = bf16 buffer [T][B][NPAD], affine + relu;  stats idx = t*KREAL + k
// Epilogue: stores pre-BN result (bf16) and accumulates column sums / sumsq.
// ---------------------------------------------------------------------------
template <int KREAL, int NOUT, int MODE>
__global__ void gemm_kernel(const void* __restrict__ Asrc,
                            const float* __restrict__ W,          // [T][KREAL][NOUT]
                            const float* __restrict__ sumIn,
                            const float* __restrict__ sqIn,
                            const float* __restrict__ gIn,        // [T][KREAL]
                            const float* __restrict__ bIn,        // [T][KREAL]
                            u16* __restrict__ Hout,               // [T][B][NPAD]
                            float* __restrict__ sumArr,           // [T][NOUT]
                            float* __restrict__ sqArr) {          // [T][NOUT]
    __shared__ __align__(16) u16 Alds[128 * KP];   // 32 KB, 16B-chunk XOR swizzle
    __shared__ __align__(16) u16 Blds[NPAD * KP];  // 28 KB, B stored transposed [n][k]
    __shared__ float s_sum[NPAD], s_sq[NPAD];
    __shared__ float aAffL[128], cAffL[128];

    const int tid = threadIdx.x;
    const int mt = blockIdx.x;
    const int t  = blockIdx.y;
    const int brow0 = mt * 128;

    // zero LDS (padding must be 0 on the B side) + in-kernel BN finalize
    {
        uint4 z = {0, 0, 0, 0};
        uint4* a4 = (uint4*)Alds;
        uint4* b4 = (uint4*)Blds;
        for (int i = tid; i < 128 * KP / 8; i += 256) a4[i] = z;
        for (int i = tid; i < NPAD * KP / 8; i += 256) b4[i] = z;
        if (tid < NPAD) { s_sum[tid] = 0.f; s_sq[tid] = 0.f; }
        if (tid < KREAL) {
            int idx = (MODE == 0) ? (tid * 21 + (t + 1)) : (t * KREAL + tid);
            float m = sumIn[idx] * (1.f / BATCH);
            float v = sqIn[idx] * (1.f / BATCH) - m * m;
            float rstd = rsqrtf(v + BN_EPS);
            float ga = gIn[t * KREAL + tid] * rstd;
            aAffL[tid] = ga;
            cAffL[tid] = bIn[t * KREAL + tid] - m * ga;
        }
    }
    __syncthreads();

    // ---- stage A (affine [+relu]) as bf16, swizzled 16B chunks ----
    const int NCH = (KREAL + 7) / 8;   // chunks containing real data
    for (int cidx = tid; cidx < 128 * NCH; cidx += 256) {
        int row = cidx / NCH;
        int kc  = cidx % NCH;
        int k0  = kc * 8;
        float v[8];
        if (MODE == 0) {
            const float* xrow = (const float*)Asrc + (size_t)(brow0 + row) * 2100 + (t + 1);
#pragma unroll
            for (int j = 0; j < 8; j++) {
                int k = k0 + j;
                v[j] = (k < KREAL) ? (xrow[k * 21] * aAffL[k] + cAffL[k]) : 0.f;
            }
        } else {
            const u16* hrow = (const u16*)Asrc + ((size_t)t * BATCH + brow0 + row) * NPAD + k0;
            u16 hv[8];
            *(uint4*)hv = *(const uint4*)hrow;
#pragma unroll
            for (int j = 0; j < 8; j++) {
                int k = k0 + j;
                float hf = bf2f(hv[j]);
                float av = (k < KREAL) ? fmaf(hf, aAffL[k], cAffL[k]) : 0.f;
                v[j] = fmaxf(av, 0.f);
            }
        }
        u16 pk[8];
#pragma unroll
        for (int j = 0; j < 8; j++) pk[j] = f2bf(v[j]);
        int swc = kc ^ (row & 7);
        *(uint4*)&Alds[row * KP + swc * 8] = *(uint4*)pk;
    }

    // ---- stage B transposed: Blds[n][k] = W[t][k][n] (coalesced global reads) ----
    const float* Wt = W + (size_t)t * KREAL * NOUT;
    for (int i = tid; i < KREAL * NOUT; i += 256) {
        int k = i / NOUT, n = i % NOUT;
        int swc = (k >> 3) ^ (n & 7);
        Blds[n * KP + swc * 8 + (k & 7)] = f2bf(Wt[i]);
    }
    __syncthreads();

    // ---- MFMA: wave owns 32 rows x 112 cols = 2 m-frags x 7 n-frags ----
    const int lane = tid & 63;
    const int wv   = tid >> 6;
    const int r0   = lane & 15;
    const int q    = lane >> 4;
    const int moff = wv * 32;

    v4f acc[2][7];
#pragma unroll
    for (int i = 0; i < 2; i++)
#pragma unroll
        for (int j = 0; j < 7; j++) { v4f z = {0.f, 0.f, 0.f, 0.f}; acc[i][j] = z; }

#pragma unroll
    for (int ks = 0; ks < 4; ks++) {
        int cbase = ks * 4 + q;
        v8bf afr[2];
#pragma unroll
        for (int mf = 0; mf < 2; mf++) {
            int row = moff + mf * 16 + r0;
            afr[mf] = *(const v8bf*)&Alds[row * KP + ((cbase ^ (row & 7)) * 8)];
        }
#pragma unroll
        for (int nf = 0; nf < 7; nf++) {
            int nr = nf * 16 + r0;
            v8bf bfr = *(const v8bf*)&Blds[nr * KP + ((cbase ^ (nr & 7)) * 8)];
            acc[0][nf] = __builtin_amdgcn_mfma_f32_16x16x32_bf16(afr[0], bfr, acc[0][nf], 0, 0, 0);
            acc[1][nf] = __builtin_amdgcn_mfma_f32_16x16x32_bf16(afr[1], bfr, acc[1][nf], 0, 0, 0);
        }
    }

    // ---- epilogue: store bf16 pre-BN values + column stats ----
#pragma unroll
    for (int mf = 0; mf < 2; mf++) {
#pragma unroll
        for (int nf = 0; nf < 7; nf++) {
            int n = nf * 16 + r0;
#pragma unroll
            for (int rg = 0; rg < 4; rg++) {
                int grow = brow0 + moff + mf * 16 + q * 4 + rg;
                Hout[((size_t)t * BATCH + grow) * NPAD + n] = f2bf(acc[mf][nf][rg]);
            }
        }
    }
#pragma unroll
    for (int nf = 0; nf < 7; nf++) {
        float cs = 0.f, cq = 0.f;
#pragma unroll
        for (int mf = 0; mf < 2; mf++)
#pragma unroll
            for (int rg = 0; rg < 4; rg++) {
                float vv = acc[mf][nf][rg];
                cs += vv; cq += vv * vv;
            }
        cs += __shfl_xor(cs, 16); cs += __shfl_xor(cs, 32);
        cq += __shfl_xor(cq, 16); cq += __shfl_xor(cq, 32);
        if (q == 0) {
            atomicAdd(&s_sum[nf * 16 + r0], cs);
            atomicAdd(&s_sq[nf * 16 + r0], cq);
        }
    }
    __syncthreads();
    if (tid < NOUT) {
        atomicAdd(&sumArr[t * NOUT + tid], s_sum[tid]);
        atomicAdd(&sqArr[t * NOUT + tid], s_sq[tid]);
    }
}

// ---------------------------------------------------------------------------
// Scan: lane-per-timestep (20 lanes per batch row, 3 rows per wave).
// a3/c3 computed in-kernel from sum3/sq3 (folds finalize; scale = 1/D).
// ---------------------------------------------------------------------------
__global__ void scan_kernel(const float* __restrict__ dw,
                            const u16* __restrict__ zbuf,         // [T][B][NPAD]
                            const float* __restrict__ sum3, const float* __restrict__ sq3,
                            const float* __restrict__ g3, const float* __restrict__ b3,
                            const float* __restrict__ z_init, const float* __restrict__ y_init,
                            float* __restrict__ yout, float* __restrict__ meanout) {
    __shared__ float a3l[TSUB * DIM], c3l[TSUB * DIM], zil[DIM];
    __shared__ float bsum[NSTEP];
    const int tid = threadIdx.x;
    for (int i = tid; i < TSUB * DIM; i += 256) {
        float m = sum3[i] * (1.f / BATCH);
        float v = sq3[i] * (1.f / BATCH) - m * m;
        float rstd = rsqrtf(v + BN_EPS);
        float ga = g3[i] * rstd;
        a3l[i] = ga * (1.f / DIM);
        c3l[i] = (b3[i] - m * ga) * (1.f / DIM);
    }
    if (tid < DIM) zil[tid] = z_init[tid];
    if (tid < NSTEP) bsum[tid] = 0.f;
    __syncthreads();

    const int wv = tid >> 6, lane = tid & 63;
    const int g = lane / 20, n = lane - g * 20;       // g==3 -> idle lanes 60..63
    const int b = (blockIdx.x * 4 + wv) * 3 + g;
    const bool active = (g < 3) && (b < BATCH);

    float dot = 0.f;
    if (active) {
        const float* dwb = dw + (size_t)b * (DIM * NSTEP) + n;
        if (n == 0) {
#pragma unroll 4
            for (int d = 0; d < DIM; d += 4) {
                float w0 = dwb[d * NSTEP], w1 = dwb[(d + 1) * NSTEP];
                float w2 = dwb[(d + 2) * NSTEP], w3 = dwb[(d + 3) * NSTEP];
                dot += zil[d] * w0 + zil[d + 1] * w1 + zil[d + 2] * w2 + zil[d + 3] * w3;
            }
        } else {
            const int t = n - 1;
            const u16* zr = zbuf + ((size_t)t * BATCH + b) * NPAD;
            const float* al = a3l + t * DIM;
            const float* cl = c3l + t * DIM;
            for (int dc = 0; dc < 12; dc++) {
                u16 hv[8];
                *(uint4*)hv = *(const uint4*)(zr + dc * 8);
                float wv8[8];
#pragma unroll
                for (int j = 0; j < 8; j++) wv8[j] = dwb[(dc * 8 + j) * NSTEP];
#pragma unroll
                for (int j = 0; j < 8; j++) {
                    int d = dc * 8 + j;
                    dot += fmaf(bf2f(hv[j]), al[d], cl[d]) * wv8[j];
                }
            }
#pragma unroll
            for (int d = 96; d < DIM; d++) {
                float zv = fmaf(bf2f(zr[d]), al[d], cl[d]);
                dot += zv * dwb[d * NSTEP];
            }
        }
    }

    const float yi = y_init[0];
    float y = yi, ysave = 0.f;
#pragma unroll
    for (int i = 0; i < NSTEP; i++) {
        float dv = __shfl(dot, g * 20 + i, 64);
        y = y - DT_C * __sinf(y) + dv;
        if (i == n - 1) ysave = y;                    // lane n holds y_n (n>=1)
    }
    if (active && n == 0) yout[b] = y;                // y_final = y_20
    if (active && n >= 1) atomicAdd(&bsum[n], ysave);
    __syncthreads();
    if (tid >= 1 && tid < NSTEP) atomicAdd(&meanout[tid], bsum[tid] * (1.f / BATCH));
    if (blockIdx.x == 0 && tid == 0) meanout[0] = yi; // mean of constant y0
}

// ---------------------------------------------------------------------------
extern "C" void kernel_launch(void* const* d_in, const int* in_sizes, int n_in,
                              void* d_out, int out_size, void* d_ws, size_t ws_size,
                              hipStream_t stream) {
    const float* dw     = (const float*)d_in[0];
    const float* x      = (const float*)d_in[1];
    const float* y_init = (const float*)d_in[3];
    const float* z_init = (const float*)d_in[4];
    const float* g0 = (const float*)d_in[5];
    const float* b0 = (const float*)d_in[6];
    const float* W0 = (const float*)d_in[7];
    const float* g1 = (const float*)d_in[8];
    const float* b1 = (const float*)d_in[9];
    const float* W1 = (const float*)d_in[10];
    const float* g2 = (const float*)d_in[11];
    const float* b2 = (const float*)d_in[12];
    const float* W2 = (const float*)d_in[13];
    // d_in[14] = bias2: cancelled by the following BatchNorm -> unused
    const float* g3 = (const float*)d_in[15];
    const float* b3 = (const float*)d_in[16];

    char* ws = (char*)d_ws;
    size_t off = 0;
    auto alloc = [&](size_t bytes) -> void* {
        off = (off + 255) & ~(size_t)255;
        void* p = ws + off;
        off += bytes;
        return p;
    };

    // stats block (memset to 0 each launch)
    const int nStats = 4200 + TSUB * HID * 2 * 2 + TSUB * DIM * 2;  // 16360 floats
    float* statsBlk = (float*)alloc((size_t)nStats * 4);
    float* sum0 = statsBlk;            float* sq0  = sum0 + 2100;   // contiguous [sum|sq]
    float* sum1 = sum0 + 4200;         float* sq1  = sum1 + TSUB * HID;
    float* sum2 = sq1 + TSUB * HID;    float* sq2  = sum2 + TSUB * HID;
    float* sum3 = sq2 + TSUB * HID;    float* sq3  = sum3 + TSUB * DIM;

    const size_t hBytes = (size_t)TSUB * BATCH * NPAD * 2;   // ~34.9 MB
    u16* h0 = (u16*)alloc(hBytes);
    u16* h1 = (u16*)alloc(hBytes);
    u16* outbuf = h0;                     // h0 dead once gemm1 consumed it
    float* part = (float*)h1;             // stats partials alias h1 (dead before gemm1)

    float* yout = (float*)d_out;
    float* meanout = yout + BATCH;

    hipMemsetAsync(statsBlk, 0, (size_t)nStats * 4, stream);
    hipMemsetAsync(meanout, 0, NSTEP * 4, stream);

    stats0A<<<SB, 256, 0, stream>>>(x, part);
    stats0B<<<(4200 * SLICES + 255) / 256, 256, 0, stream>>>(part, sum0);

    gemm_kernel<DIM, HID, 0><<<dim3(64, TSUB), 256, 0, stream>>>(x, W0, sum0, sq0, g0, b0, h0, sum1, sq1);
    gemm_kernel<HID, HID, 1><<<dim3(64, TSUB), 256, 0, stream>>>(h0, W1, sum1, sq1, g1, b1, h1, sum2, sq2);
    gemm_kernel<HID, DIM, 1><<<dim3(64, TSUB), 256, 0, stream>>>(h1, W2, sum2, sq2, g2, b2, outbuf, sum3, sq3);

    scan_kernel<<<683, 256, 0, stream>>>(dw, outbuf, sum3, sq3, g3, b3, z_init, y_init, yout, meanout);
}

// Round 3
// 189.244 us; speedup vs baseline: 1.9952x; 1.2902x over previous
//
#include <hip/hip_runtime.h>

typedef unsigned short u16;
typedef unsigned int   u32;

#define BATCH  8192
#define DIM    100      // D
#define HID    110      // H
#define TSUB   19       // T = N-1 subnets
#define NSTEP  20       // N scan steps
#define KP     128      // padded K for MFMA
#define NPAD   112      // padded N (output cols) for tiles/storage
#define BN_EPS 1e-6f
#define DT_C   0.05f

#define SAB  1024                 // statsA blocks
#define SAR  (BATCH / SAB)        // 8 rows per block
#define SLICES 32                 // statsB slices (1024/32 = 32 rows per slice)

typedef __bf16 v8bf __attribute__((ext_vector_type(8)));
typedef float  v4f  __attribute__((ext_vector_type(4)));
typedef u16    u16x4 __attribute__((ext_vector_type(4)));

__device__ __forceinline__ u16 f2bf(float f) {
    u32 u = __float_as_uint(f);
    return (u16)((u + 0x7fffu + ((u >> 16) & 1u)) >> 16);   // RNE
}
__device__ __forceinline__ float bf2f(u16 h) {
    return __uint_as_float(((u32)h) << 16);
}
__device__ __forceinline__ void acc4(float4& s, float4& q, float4 v) {
    s.x += v.x; s.y += v.y; s.z += v.z; s.w += v.w;
    q.x += v.x * v.x; q.y += v.y * v.y; q.z += v.z * v.z; q.w += v.w * v.w;
}

// ---------------------------------------------------------------------------
// statsA: stream x coalesced once; produce (a) per-block partial column sums
// [SAB][4200] and (b) the transposed bf16 activation xT[t][b][d] (NPAD rows).
// ---------------------------------------------------------------------------
__global__ void statsA(const float* __restrict__ x, float* __restrict__ part,
                       u32* __restrict__ xT32) {
    __shared__ u16 xls[SAR][2112];
    const int tid = threadIdx.x;
    const int b0 = blockIdx.x * SAR;
    float4 s0 = {0,0,0,0}, q0 = {0,0,0,0};
    float4 s1 = {0,0,0,0}, q1 = {0,0,0,0};
    float4 s2 = {0,0,0,0}, q2 = {0,0,0,0};
#pragma unroll
    for (int r = 0; r < SAR; r++) {
        const float4* row = (const float4*)(x + (size_t)(b0 + r) * 2100);
        float4 v0 = row[tid];
        float4 v1 = row[tid + 256];
        acc4(s0, q0, v0);
        acc4(s1, q1, v1);
        u16x4 p0 = { f2bf(v0.x), f2bf(v0.y), f2bf(v0.z), f2bf(v0.w) };
        u16x4 p1 = { f2bf(v1.x), f2bf(v1.y), f2bf(v1.z), f2bf(v1.w) };
        *(u16x4*)&xls[r][tid * 4]        = p0;
        *(u16x4*)&xls[r][1024 + tid * 4] = p1;
        if (tid < 13) {
            float4 v2 = row[tid + 512];
            acc4(s2, q2, v2);
            u16x4 p2 = { f2bf(v2.x), f2bf(v2.y), f2bf(v2.z), f2bf(v2.w) };
            *(u16x4*)&xls[r][2048 + tid * 4] = p2;
        }
    }
    float* ps = part + (size_t)blockIdx.x * 4200;
    *(float4*)&ps[tid * 4]               = s0;
    *(float4*)&ps[1024 + tid * 4]        = s1;
    *(float4*)&ps[2100 + tid * 4]        = q0;
    *(float4*)&ps[2100 + 1024 + tid * 4] = q1;
    if (tid < 13) {
        *(float4*)&ps[2048 + tid * 4]        = s2;
        *(float4*)&ps[2100 + 2048 + tid * 4] = q2;
    }
    __syncthreads();
    // write xT[t][b0+r][0..111] as u32 pairs (coalesced 224B segments)
    const int TOT = TSUB * SAR * (NPAD / 2);   // 19*8*56
    for (int i = tid; i < TOT; i += 256) {
        int w = i % (NPAD / 2);
        int seg = i / (NPAD / 2);
        int r = seg % SAR, t = seg / SAR;
        int d0 = w * 2;
        u32 v = 0;
        if (d0 < DIM) {
            u16 lo = xls[r][d0 * 21 + t + 1];
            u16 hi = (d0 + 1 < DIM) ? xls[r][(d0 + 1) * 21 + t + 1] : (u16)0;
            v = (u32)lo | ((u32)hi << 16);
        }
        xT32[((size_t)t * BATCH + b0 + r) * (NPAD / 2) + w] = v;
    }
}

// statsB: out[o] = sum over SAB partial rows (SLICES slices, atomic combine)
__global__ void statsB(const float* __restrict__ part, float* __restrict__ out) {
    int gid = blockIdx.x * 256 + threadIdx.x;
    if (gid >= 4200 * SLICES) return;
    int slice = gid / 4200;
    int o = gid - slice * 4200;
    const float* p = part + (size_t)slice * (SAB / SLICES) * 4200 + o;
    float acc = 0.f;
#pragma unroll 4
    for (int i = 0; i < SAB / SLICES; i++) acc += p[(size_t)i * 4200];
    atomicAdd(&out[o], acc);
}

// ---------------------------------------------------------------------------
// wtrans: W[l][t][k][n] f32 -> WTsw[l][t][n][chunk-swizzled k] bf16, zero-pad
// to [112][128]. Pre-applies the LDS XOR swizzle so GEMM B-staging is a copy.
// ---------------------------------------------------------------------------
__global__ void wtrans(const float* __restrict__ W0, const float* __restrict__ W1,
                       const float* __restrict__ W2, u16* __restrict__ WTsw) {
    __shared__ float lw[HID * HID];
    const int t = blockIdx.x, l = blockIdx.y, tid = threadIdx.x;
    const float* W; int K, N;
    if (l == 0)      { W = W0; K = DIM; N = HID; }
    else if (l == 1) { W = W1; K = HID; N = HID; }
    else             { W = W2; K = HID; N = DIM; }
    const float* Wt = W + (size_t)t * K * N;
    for (int i = tid; i < K * N; i += 256) lw[i] = Wt[i];
    __syncthreads();
    u16* out = WTsw + ((size_t)l * TSUB + t) * (NPAD * KP);
    for (int i = tid; i < NPAD * 16; i += 256) {
        int n = i / 16, p = i % 16;
        int kc = p ^ (n & 7);
        u16 o8[8];
#pragma unroll
        for (int j = 0; j < 8; j++) {
            int k = kc * 8 + j;
            float v = (k < K && n < N) ? lw[k * N + n] : 0.f;
            o8[j] = f2bf(v);
        }
        *(uint4*)&out[(size_t)n * KP + p * 8] = *(uint4*)o8;
    }
}

// ---------------------------------------------------------------------------
// GEMM: per (t, m-tile) block. C[128 x NPAD] = affine(A)[128 x KREAL] @ W
// A = bf16 [T][B][NPAD]; B = pre-swizzled WTsw plane (straight uint4 copy).
// BN finalize in-kernel. IDXMODE 0: stats idx = k*21+(t+1); 1: t*KREAL+k.
// Epilogue: bf16 pre-BN store + column sum/sumsq atomics.
// ---------------------------------------------------------------------------
template <int KREAL, int NOUT, int IDXMODE, int RELU>
__global__ void gemm_kernel(const u16* __restrict__ Ain,
                            const u16* __restrict__ WTswL,        // [T][NPAD][KP]
                            const float* __restrict__ sumIn,
                            const float* __restrict__ sqIn,
                            const float* __restrict__ gIn,
                            const float* __restrict__ bIn,
                            u16* __restrict__ Hout,               // [T][B][NPAD]
                            float* __restrict__ sumArr,
                            float* __restrict__ sqArr) {
    __shared__ __align__(16) u16 Alds[128 * KP];   // 32 KB, 16B-chunk XOR swizzle
    __shared__ __align__(16) u16 Blds[NPAD * KP];  // 28 KB, pre-swizzled image
    __shared__ float s_sum[NPAD], s_sq[NPAD];
    __shared__ float aAffL[KP], cAffL[KP];

    const int tid = threadIdx.x;
    const int mt = blockIdx.x;
    const int t  = blockIdx.y;
    const int brow0 = mt * 128;

    if (tid < NPAD) { s_sum[tid] = 0.f; s_sq[tid] = 0.f; }
    if (tid < KREAL) {
        int idx = (IDXMODE == 0) ? (tid * 21 + (t + 1)) : (t * KREAL + tid);
        float m = sumIn[idx] * (1.f / BATCH);
        float v = sqIn[idx] * (1.f / BATCH) - m * m;
        float rstd = rsqrtf(v + BN_EPS);
        float ga = gIn[t * KREAL + tid] * rstd;
        aAffL[tid] = ga;
        cAffL[tid] = bIn[t * KREAL + tid] - m * ga;
    }

    // ---- stage B: straight copy of pre-swizzled plane ----
    {
        const uint4* wsrc = (const uint4*)(WTswL + (size_t)t * NPAD * KP);
        uint4* bl = (uint4*)Blds;
#pragma unroll
        for (int i = 0; i < 7; i++) bl[tid + i * 256] = wsrc[tid + i * 256];
    }
    // zero A chunks that staging won't write (kc >= NCH)
    const int NCH = (KREAL + 7) / 8;
    for (int i = tid; i < 128 * (16 - NCH); i += 256) {
        int row = i / (16 - NCH);
        int kc  = NCH + i % (16 - NCH);
        uint4 z = {0, 0, 0, 0};
        *(uint4*)&Alds[row * KP + (kc ^ (row & 7)) * 8] = z;
    }
    __syncthreads();   // aAffL ready (also covers LDS zero/copy ordering)

    // ---- stage A (affine [+relu]) as bf16, swizzled 16B chunks ----
    for (int cidx = tid; cidx < 128 * NCH; cidx += 256) {
        int row = cidx / NCH;
        int kc  = cidx % NCH;
        int k0  = kc * 8;
        const u16* hrow = Ain + ((size_t)t * BATCH + brow0 + row) * NPAD + k0;
        u16 hv[8];
        *(uint4*)hv = *(const uint4*)hrow;
        u16 pk[8];
#pragma unroll
        for (int j = 0; j < 8; j++) {
            int k = k0 + j;
            float av = (k < KREAL) ? fmaf(bf2f(hv[j]), aAffL[k], cAffL[k]) : 0.f;
            if (RELU) av = fmaxf(av, 0.f);
            pk[j] = f2bf(av);
        }
        *(uint4*)&Alds[row * KP + ((kc ^ (row & 7)) * 8)] = *(uint4*)pk;
    }
    __syncthreads();

    // ---- MFMA: wave owns 32 rows x 112 cols = 2 m-frags x 7 n-frags ----
    const int lane = tid & 63;
    const int wv   = tid >> 6;
    const int r0   = lane & 15;
    const int q    = lane >> 4;
    const int moff = wv * 32;

    v4f acc[2][7];
#pragma unroll
    for (int i = 0; i < 2; i++)
#pragma unroll
        for (int j = 0; j < 7; j++) { v4f z = {0.f, 0.f, 0.f, 0.f}; acc[i][j] = z; }

#pragma unroll
    for (int ks = 0; ks < 4; ks++) {
        int cbase = ks * 4 + q;
        v8bf afr[2];
#pragma unroll
        for (int mf = 0; mf < 2; mf++) {
            int row = moff + mf * 16 + r0;
            afr[mf] = *(const v8bf*)&Alds[row * KP + ((cbase ^ (row & 7)) * 8)];
        }
#pragma unroll
        for (int nf = 0; nf < 7; nf++) {
            int nr = nf * 16 + r0;
            v8bf bfr = *(const v8bf*)&Blds[nr * KP + ((cbase ^ (nr & 7)) * 8)];
            acc[0][nf] = __builtin_amdgcn_mfma_f32_16x16x32_bf16(afr[0], bfr, acc[0][nf], 0, 0, 0);
            acc[1][nf] = __builtin_amdgcn_mfma_f32_16x16x32_bf16(afr[1], bfr, acc[1][nf], 0, 0, 0);
        }
    }

    // ---- epilogue: store bf16 pre-BN values + column stats ----
#pragma unroll
    for (int mf = 0; mf < 2; mf++) {
#pragma unroll
        for (int nf = 0; nf < 7; nf++) {
            int n = nf * 16 + r0;
#pragma unroll
            for (int rg = 0; rg < 4; rg++) {
                int grow = brow0 + moff + mf * 16 + q * 4 + rg;
                Hout[((size_t)t * BATCH + grow) * NPAD + n] = f2bf(acc[mf][nf][rg]);
            }
        }
    }
#pragma unroll
    for (int nf = 0; nf < 7; nf++) {
        float cs = 0.f, cq = 0.f;
#pragma unroll
        for (int mf = 0; mf < 2; mf++)
#pragma unroll
            for (int rg = 0; rg < 4; rg++) {
                float vv = acc[mf][nf][rg];
                cs += vv; cq += vv * vv;
            }
        cs += __shfl_xor(cs, 16); cs += __shfl_xor(cs, 32);
        cq += __shfl_xor(cq, 16); cq += __shfl_xor(cq, 32);
        if (q == 0) {
            atomicAdd(&s_sum[nf * 16 + r0], cs);
            atomicAdd(&s_sq[nf * 16 + r0], cq);
        }
    }
    __syncthreads();
    if (tid < NOUT) {
        atomicAdd(&sumArr[t * NOUT + tid], s_sum[tid]);
        atomicAdd(&sqArr[t * NOUT + tid], s_sq[tid]);
    }
}

// ---------------------------------------------------------------------------
// Scan: lane-per-timestep (20 lanes per batch row, 3 rows per wave).
// ---------------------------------------------------------------------------
__global__ void scan_kernel(const float* __restrict__ dw,
                            const u16* __restrict__ zbuf,         // [T][B][NPAD]
                            const float* __restrict__ sum3, const float* __restrict__ sq3,
                            const float* __restrict__ g3, const float* __restrict__ b3,
                            const float* __restrict__ z_init, const float* __restrict__ y_init,
                            float* __restrict__ yout, float* __restrict__ meanout) {
    __shared__ float a3l[TSUB * DIM], c3l[TSUB * DIM], zil[DIM];
    __shared__ float bsum[NSTEP];
    const int tid = threadIdx.x;
    for (int i = tid; i < TSUB * DIM; i += 256) {
        float m = sum3[i] * (1.f / BATCH);
        float v = sq3[i] * (1.f / BATCH) - m * m;
        float rstd = rsqrtf(v + BN_EPS);
        float ga = g3[i] * rstd;
        a3l[i] = ga * (1.f / DIM);
        c3l[i] = (b3[i] - m * ga) * (1.f / DIM);
    }
    if (tid < DIM) zil[tid] = z_init[tid];
    if (tid < NSTEP) bsum[tid] = 0.f;
    __syncthreads();

    const int wv = tid >> 6, lane = tid & 63;
    const int g = lane / 20, n = lane - g * 20;
    const int b = (blockIdx.x * 4 + wv) * 3 + g;
    const bool active = (g < 3) && (b < BATCH);

    float dot = 0.f;
    if (active) {
        const float* dwb = dw + (size_t)b * (DIM * NSTEP) + n;
        if (n == 0) {
#pragma unroll 4
            for (int d = 0; d < DIM; d += 4) {
                float w0 = dwb[d * NSTEP], w1 = dwb[(d + 1) * NSTEP];
                float w2 = dwb[(d + 2) * NSTEP], w3 = dwb[(d + 3) * NSTEP];
                dot += zil[d] * w0 + zil[d + 1] * w1 + zil[d + 2] * w2 + zil[d + 3] * w3;
            }
        } else {
            const int t = n - 1;
            const u16* zr = zbuf + ((size_t)t * BATCH + b) * NPAD;
            const float* al = a3l + t * DIM;
            const float* cl = c3l + t * DIM;
            for (int dc = 0; dc < 12; dc++) {
                u16 hv[8];
                *(uint4*)hv = *(const uint4*)(zr + dc * 8);
                float wv8[8];
#pragma unroll
                for (int j = 0; j < 8; j++) wv8[j] = dwb[(dc * 8 + j) * NSTEP];
#pragma unroll
                for (int j = 0; j < 8; j++) {
                    int d = dc * 8 + j;
                    dot += fmaf(bf2f(hv[j]), al[d], cl[d]) * wv8[j];
                }
            }
#pragma unroll
            for (int d = 96; d < DIM; d++) {
                float zv = fmaf(bf2f(zr[d]), al[d], cl[d]);
                dot += zv * dwb[d * NSTEP];
            }
        }
    }

    const float yi = y_init[0];
    float y = yi, ysave = 0.f;
#pragma unroll
    for (int i = 0; i < NSTEP; i++) {
        float dv = __shfl(dot, g * 20 + i, 64);
        y = y - DT_C * __sinf(y) + dv;
        if (i == n - 1) ysave = y;
    }
    if (active && n == 0) yout[b] = y;
    if (active && n >= 1) atomicAdd(&bsum[n], ysave);
    __syncthreads();
    if (tid >= 1 && tid < NSTEP) atomicAdd(&meanout[tid], bsum[tid] * (1.f / BATCH));
    if (blockIdx.x == 0 && tid == 0) meanout[0] = yi;
}

// ---------------------------------------------------------------------------
extern "C" void kernel_launch(void* const* d_in, const int* in_sizes, int n_in,
                              void* d_out, int out_size, void* d_ws, size_t ws_size,
                              hipStream_t stream) {
    const float* dw     = (const float*)d_in[0];
    const float* x      = (const float*)d_in[1];
    const float* y_init = (const float*)d_in[3];
    const float* z_init = (const float*)d_in[4];
    const float* g0 = (const float*)d_in[5];
    const float* b0 = (const float*)d_in[6];
    const float* W0 = (const float*)d_in[7];
    const float* g1 = (const float*)d_in[8];
    const float* b1 = (const float*)d_in[9];
    const float* W1 = (const float*)d_in[10];
    const float* g2 = (const float*)d_in[11];
    const float* b2 = (const float*)d_in[12];
    const float* W2 = (const float*)d_in[13];
    // d_in[14] = bias2: cancelled by the following BatchNorm -> unused
    const float* g3 = (const float*)d_in[15];
    const float* b3 = (const float*)d_in[16];

    char* ws = (char*)d_ws;
    size_t off = 0;
    auto alloc = [&](size_t bytes) -> void* {
        off = (off + 255) & ~(size_t)255;
        void* p = ws + off;
        off += bytes;
        return p;
    };

    const int nStats = 4200 + TSUB * HID * 2 * 2 + TSUB * DIM * 2;  // 16360 floats
    float* statsBlk = (float*)alloc((size_t)nStats * 4);
    float* sum0 = statsBlk;            float* sq0  = sum0 + 2100;
    float* sum1 = sum0 + 4200;         float* sq1  = sum1 + TSUB * HID;
    float* sum2 = sq1 + TSUB * HID;    float* sq2  = sum2 + TSUB * HID;
    float* sum3 = sq2 + TSUB * HID;    float* sq3  = sum3 + TSUB * DIM;

    u16* WTsw = (u16*)alloc((size_t)3 * TSUB * NPAD * KP * 2);      // 1.63 MB

    const size_t hBytes = (size_t)TSUB * BATCH * NPAD * 2;          // ~34.9 MB
    u16* h0 = (u16*)alloc(hBytes);
    u16* h1 = (u16*)alloc(hBytes);
    u16* outbuf = h0;                 // h0 dead once gemm1 consumed it
    float* part = (float*)h0;         // stats partials alias h0 (dead before gemm0 writes)
    u32*  xT32  = (u32*)h1;           // xT aliases h1 (dead after gemm0; gemm1 then writes h1)

    float* yout = (float*)d_out;
    float* meanout = yout + BATCH;

    hipMemsetAsync(statsBlk, 0, (size_t)nStats * 4, stream);
    hipMemsetAsync(meanout, 0, NSTEP * 4, stream);

    wtrans<<<dim3(TSUB, 3), 256, 0, stream>>>(W0, W1, W2, WTsw);
    statsA<<<SAB, 256, 0, stream>>>(x, part, xT32);
    statsB<<<(4200 * SLICES + 255) / 256, 256, 0, stream>>>(part, sum0);

    const u16* xT = (const u16*)xT32;
    u16* WT0 = WTsw;
    u16* WT1 = WTsw + (size_t)TSUB * NPAD * KP;
    u16* WT2 = WTsw + (size_t)2 * TSUB * NPAD * KP;

    gemm_kernel<DIM, HID, 0, 0><<<dim3(64, TSUB), 256, 0, stream>>>(xT, WT0, sum0, sq0, g0, b0, h0, sum1, sq1);
    gemm_kernel<HID, HID, 1, 1><<<dim3(64, TSUB), 256, 0, stream>>>(h0, WT1, sum1, sq1, g1, b1, h1, sum2, sq2);
    gemm_kernel<HID, DIM, 1, 1><<<dim3(64, TSUB), 256, 0, stream>>>(h1, WT2, sum2, sq2, g2, b2, outbuf, sum3, sq3);

    scan_kernel<<<683, 256, 0, stream>>>(dw, outbuf, sum3, sq3, g3, b3, z_init, y_init, yout, meanout);
}